// Round 3
// baseline (579.665 us; speedup 1.0000x reference)
//
#include <hip/hip_runtime.h>
#include <hip/hip_bf16.h>

// Problem dims (fixed)
#define BB 8
#define TT 1024
#define DD 1024
#define HH 16
#define AA 64
#define EE 262144

typedef unsigned short u16;
typedef unsigned int u32;
typedef short bf16x4 __attribute__((ext_vector_type(4)));
typedef short bf16x8 __attribute__((ext_vector_type(8)));
typedef float f32x4 __attribute__((ext_vector_type(4)));

__device__ __forceinline__ float bf2f(u16 u) {
    union { float f; u32 i; } c; c.i = ((u32)u) << 16; return c.f;
}
__device__ __forceinline__ u16 f2bf(float f) {
    union { float f; u32 i; } c; c.f = f;
    u32 x = c.i;
    return (u16)((x + 0x7FFFu + ((x >> 16) & 1u)) >> 16);
}
// packed 2xf32 -> 2xbf16 (v_cvt_pk_bf16_f32 on gfx950)
__device__ __forceinline__ u32 pack2bf(float a, float b) {
    union { __hip_bfloat162 h; u32 u; } c;
    c.h = __float22bfloat162_rn(float2{a, b});
    return c.u;
}
// native exp2 (v_exp_f32)
__device__ __forceinline__ float fast_exp2(float x) {
#if __has_builtin(__builtin_amdgcn_exp2f)
    return __builtin_amdgcn_exp2f(x);
#else
    float r;
    asm("v_exp_f32 %0, %1" : "=v"(r) : "v"(x));
    return r;
#endif
}

// log2(e) folded scales: softmax computed as exp2( log2e * (s/8 + bias*ksum/8 - 20) )
#define QSCALE 0.18033688f          // 0.125 * 1.44269504
#define SOFT_OFF -28.8539008f       // -20 * 1.44269504

// async 16B global->LDS (per-lane gptr; LDS dest = wave-uniform base + lane*16)
#define GLDS16(gp, lp)                                                        \
    __builtin_amdgcn_global_load_lds(                                         \
        (const __attribute__((address_space(1))) u32*)(const void*)(gp),      \
        (__attribute__((address_space(3))) u32*)(void*)(lp), 16, 0, 0)

#define MFMA(a, b, c) __builtin_amdgcn_mfma_f32_16x16x32_bf16((a), (b), (c), 0, 0, 0)

// ---------------------------------------------------------------------------
// prep1: fused independent prep work, partitioned by blockIdx.x
//  [0,4096)      cvt states -> sbf
//  [4096,8192)   cvt key_states -> kbf
//  [8192,12288)  mbinit (masks -> bf16 mb)
//  [12288,16384) idx init (-1)
//  [16384,17408) tr_w (4x 1024x1024 f32 -> bf16 transposed)
// ---------------------------------------------------------------------------
__global__ __launch_bounds__(256) void prep1(const float* __restrict__ states,
                                             const float* __restrict__ keys,
                                             const float* __restrict__ masks,
                                             const float* __restrict__ Wq,
                                             const float* __restrict__ Wk,
                                             const float* __restrict__ Wv,
                                             const float* __restrict__ Wout,
                                             u16* __restrict__ sbf,
                                             u16* __restrict__ kbf,
                                             u16* __restrict__ mb,
                                             int* __restrict__ idx,
                                             u16* __restrict__ wT) {
    __shared__ u16 t[64 * 72];
    int bi = blockIdx.x, tid = threadIdx.x;
    if (bi < 12288) {
        if (bi < 8192) {  // cvt
            const float* src = (bi < 4096) ? states : keys;
            u16* dst = (bi < 4096) ? sbf : kbf;
            size_t i = ((size_t)(bi & 4095) * 256 + tid) * 8;
            f32x4 a = *(const f32x4*)(src + i);
            f32x4 b = *(const f32x4*)(src + i + 4);
            u32 o[4];
            o[0] = pack2bf(a[0], a[1]);
            o[1] = pack2bf(a[2], a[3]);
            o[2] = pack2bf(b[0], b[1]);
            o[3] = pack2bf(b[2], b[3]);
            *(bf16x8*)(dst + i) = *(bf16x8*)o;
        } else {  // mbinit
            size_t i = ((size_t)(bi - 8192) * 256 + tid) * 8;
            f32x4 a = *(const f32x4*)(masks + i);
            f32x4 b = *(const f32x4*)(masks + i + 4);
            const u16 M = f2bf(-1.0e30f);
            bf16x8 o;
#pragma unroll
            for (int j = 0; j < 4; j++) {
                o[j] = (short)((a[j] != 0.f) ? M : 0);
                o[4 + j] = (short)((b[j] != 0.f) ? M : 0);
            }
            *(bf16x8*)(mb + i) = o;
        }
    } else if (bi < 16384) {  // idx init
        size_t i = ((size_t)(bi - 12288) * 256 + tid) * 8;
        int4 m1 = {-1, -1, -1, -1};
        *(int4*)(idx + i) = m1;
        *(int4*)(idx + i + 4) = m1;
    } else {  // tr_w
        int zb = bi - 16384;
        int z = zb >> 8, by = (zb >> 4) & 15, bx = zb & 15;
        const float* src = (z == 0) ? Wq : (z == 1) ? Wk : (z == 2) ? Wv : Wout;
        u16* dst = wT + (size_t)z * 1048576;
        int row0 = by * 64, col0 = bx * 64;
        int r = tid >> 2, c0 = (tid & 3) * 16;
        const float* sp = src + (size_t)(row0 + r) * 1024 + col0 + c0;
        f32x4 f0 = *(const f32x4*)(sp);
        f32x4 f1 = *(const f32x4*)(sp + 4);
        f32x4 f2_ = *(const f32x4*)(sp + 8);
        f32x4 f3 = *(const f32x4*)(sp + 12);
#pragma unroll
        for (int j = 0; j < 4; j++) {
            t[r * 72 + c0 + j] = f2bf(f0[j]);
            t[r * 72 + c0 + 4 + j] = f2bf(f1[j]);
            t[r * 72 + c0 + 8 + j] = f2bf(f2_[j]);
            t[r * 72 + c0 + 12 + j] = f2bf(f3[j]);
        }
        __syncthreads();
        bf16x8 o0, o1;
#pragma unroll
        for (int j = 0; j < 8; j++) o0[j] = (short)t[(c0 + j) * 72 + r];
#pragma unroll
        for (int j = 0; j < 8; j++) o1[j] = (short)t[(c0 + 8 + j) * 72 + r];
        *(bf16x8*)(dst + (size_t)(col0 + r) * 1024 + row0 + c0) = o0;
        *(bf16x8*)(dst + (size_t)(col0 + r) * 1024 + row0 + c0 + 8) = o1;
    }
}

// ---------------------------------------------------------------------------
// scatter pass 1 — last edge index wins (numpy semantics)
// ---------------------------------------------------------------------------
__global__ __launch_bounds__(256) void scat_max(const int* __restrict__ ab,
                                                int* __restrict__ idx) {
    int e = blockIdx.x * 256 + threadIdx.x;
    int4 rec = ((const int4*)ab)[e];
    atomicMax(&idx[((((size_t)rec.y << 10) + rec.z) << 10) + rec.w], e);
}

// scatter pass 2 — winner writes prescaled bf16 value (skip masked cells)
// proj prescaled by 0.125 * log2(e) to match exp2-based softmax.
__global__ __launch_bounds__(256) void scat_res(const int* __restrict__ ab,
                                                const int* __restrict__ idx,
                                                const float* __restrict__ be,
                                                const float* __restrict__ bsc,
                                                u16* __restrict__ mb) {
    __shared__ float proj[32];
    int tid = threadIdx.x;
    if (tid < 32) {
        float s = 0.f;
        for (int a = 0; a < 64; a++) s += be[tid * 64 + a] * bsc[a];
        proj[tid] = s * QSCALE;  // fold 1/sqrt(A) * log2(e)
    }
    __syncthreads();
    int e = blockIdx.x * 256 + tid;
    int4 rec = ((const int4*)ab)[e];
    size_t cell = ((((size_t)rec.y << 10) + rec.z) << 10) + rec.w;
    if (idx[cell] == e && bf2f(mb[cell]) > -1.0e29f) mb[cell] = f2bf(proj[rec.x]);
}

// ---------------------------------------------------------------------------
// gemm5: fused QKV projection. grid (24,64): mat = x>>3 (0=Q,1=K,2=V).
// 128x128 tile, BK=64, both operands via global_load_lds w/ global-side XOR
// chunk swizzle (conflict-free unpadded LDS reads).
// mat 0: qb [B,H,T,A] bf16, scaled 0.125*log2e (exp2 softmax).
// mat 1: kb [B,H,T,A] bf16 + ksum f32 (shuffle-reduced in epilogue).
// mat 2: vT [B,H,A,T] bf16 via LDS transpose epilogue.
// ---------------------------------------------------------------------------
__global__ __launch_bounds__(256) void gemm5(const u16* __restrict__ sbf,
                                             const u16* __restrict__ kbf,
                                             const u16* __restrict__ wT,
                                             u16* __restrict__ qb,
                                             u16* __restrict__ kb,
                                             u16* __restrict__ vT,
                                             float* __restrict__ ks) {
    __shared__ u16 smem[17408];  // 34816 B: staging [0,16384) u16, transpose 128x136
    int tid = threadIdx.x;
    int wave = tid >> 6, lane = tid & 63;
    int quad = lane >> 4, l16 = lane & 15;
    int wm = wave >> 1, wn = wave & 1;
    int mat = blockIdx.x >> 3;
    int nloc = (blockIdx.x & 7) * 128;
    int mbase = blockIdx.y * 128;
    const u16* A = (mat == 0) ? sbf : kbf;
    const u16* BT = wT + (size_t)mat * 1048576;
    u16* Asm = smem;
    u16* Bsm = smem + 8192;
    f32x4 acc[4][4] = {};
    int srow = wave * 32 + (lane >> 3);
    int schunk = (lane & 7) ^ (lane >> 3);
    const u16* gA = A + (size_t)(mbase + srow) * 1024 + schunk * 8;
    const u16* gB = BT + (size_t)(nloc + srow) * 1024 + schunk * 8;
    u16* lA = Asm + wave * 2048;
    u16* lB = Bsm + wave * 2048;
    int sx = l16 & 7;
    for (int k0 = 0; k0 < 1024; k0 += 64) {
        __syncthreads();
#pragma unroll
        for (int j = 0; j < 4; j++) GLDS16(gA + k0 + j * 8192, lA + j * 512);
#pragma unroll
        for (int j = 0; j < 4; j++) GLDS16(gB + k0 + j * 8192, lB + j * 512);
        __syncthreads();
#pragma unroll
        for (int kk = 0; kk < 2; kk++) {
            bf16x8 af[4], bfr[4];
#pragma unroll
            for (int mt = 0; mt < 4; mt++)
                af[mt] = *(const bf16x8*)&Asm[(wm * 64 + mt * 16 + l16) * 64 +
                                              ((kk * 4 + quad) ^ sx) * 8];
#pragma unroll
            for (int nt = 0; nt < 4; nt++)
                bfr[nt] = *(const bf16x8*)&Bsm[(wn * 64 + nt * 16 + l16) * 64 +
                                               ((kk * 4 + quad) ^ sx) * 8];
#pragma unroll
            for (int mt = 0; mt < 4; mt++)
#pragma unroll
                for (int nt = 0; nt < 4; nt++)
                    acc[mt][nt] = MFMA(af[mt], bfr[nt], acc[mt][nt]);
        }
    }

    if (mat == 2) {
        // V: transpose through LDS -> vT [B,H,A,T]
        __syncthreads();  // all waves done with staging LDS
#pragma unroll
        for (int mt = 0; mt < 4; mt++)
#pragma unroll
            for (int nt = 0; nt < 4; nt++)
#pragma unroll
                for (int r = 0; r < 4; r++) {
                    int rowl = wm * 64 + mt * 16 + quad * 4 + r;
                    int coll = wn * 64 + nt * 16 + l16;
                    smem[coll * 136 + rowl] = f2bf(acc[mt][nt][r]);
                }
        __syncthreads();
        int b = mbase >> 10, t0 = mbase & 1023;
        int c = tid >> 1, hf = tid & 1;
        int h = (nloc >> 6) + (c >> 6);
        int a = c & 63;
        u16* dst = vT + ((((size_t)(b * 16 + h)) * 64 + a) << 10) + t0 + hf * 64;
        const u16* srcl = smem + c * 136 + hf * 64;
#pragma unroll
        for (int j = 0; j < 8; j++) *(bf16x8*)(dst + j * 8) = *(const bf16x8*)(srcl + j * 8);
    } else {
        u16* dst = (mat == 0) ? qb : kb;
        float sc = (mat == 0) ? QSCALE : 1.0f;
#pragma unroll
        for (int mt = 0; mt < 4; mt++)
#pragma unroll
            for (int nt = 0; nt < 4; nt++)
#pragma unroll
                for (int r = 0; r < 4; r++) {
                    int gm = mbase + wm * 64 + mt * 16 + quad * 4 + r;
                    int gnl = nloc + wn * 64 + nt * 16 + l16;
                    int b = gm >> 10, t = gm & 1023, h = gnl >> 6, a = gnl & 63;
                    dst[(((size_t)(b * 16 + h) * 1024) + t) * 64 + a] =
                        f2bf(acc[mt][nt][r] * sc);
                }
        if (mat == 1) {
            // ksum[b,h,t] = sum_a K (f32 acc, pre-rounding)
            int h = (nloc + wn * 64) >> 6;
#pragma unroll
            for (int mt = 0; mt < 4; mt++)
#pragma unroll
                for (int r = 0; r < 4; r++) {
                    float s = acc[mt][0][r] + acc[mt][1][r] + acc[mt][2][r] + acc[mt][3][r];
                    s += __shfl_xor(s, 1);
                    s += __shfl_xor(s, 2);
                    s += __shfl_xor(s, 4);
                    s += __shfl_xor(s, 8);
                    if (l16 == 0) {
                        int gm = mbase + wm * 64 + mt * 16 + quad * 4 + r;
                        int b = gm >> 10, t = gm & 1023;
                        ks[(((size_t)(b * 16 + h)) << 10) + t] = s;
                    }
                }
        }
    }
}

// ---------------------------------------------------------------------------
// attn6: 64-q tile (wave = 16 q-rows), K-blocks of 64, ZERO staging.
// K and V are read global->VGPR directly: per (b,h) K+V = 256 KB (L2-hot),
// per 64-block K/V tile = 8 KB each (L1-hot across the 4 waves re-reading
// it). MFMA fragment layouts map directly to coalesced global addresses
// (K is [t][a] row-major; V is pre-transposed [a][t]). No __syncthreads in
// the whole kernel -> waves are fully independent; latency is hidden by the
// per-CU wave pool (LDS down to ~9.5 KB so occupancy is wave-capped, not
// LDS-capped). Only wave-private LDS: Psm (P round-trip for the PV A-operand
// relayout) and lsm (row-sum broadcast). Softmax in exp2 domain (scales
// pre-folded with log2e); accumulator pre-biased -20*log2e.
// ---------------------------------------------------------------------------
__global__ __launch_bounds__(256) void attn6(const u16* __restrict__ qbuf,
                                             const u16* __restrict__ kbuf,
                                             const u16* __restrict__ vT,
                                             const float* __restrict__ ksum,
                                             const u16* __restrict__ mb,
                                             u16* __restrict__ ctx) {
    __shared__ u16 Psm[4 * 16 * 72];
    __shared__ float lsm[64];
    int tid = threadIdx.x;
    int wave = tid >> 6, lane = tid & 63;
    int quad = lane >> 4, l16 = lane & 15;
    int qb = blockIdx.x, h = blockIdx.y, b = blockIdx.z;
    int bh = b * 16 + h;
    const u16* qp = qbuf + (size_t)bh * 65536;
    const u16* kp = kbuf + (size_t)bh * 65536;
    const u16* vp = vT + (size_t)bh * 65536;
    const float* ksp = ksum + (size_t)bh * 1024;
    int q0 = qb * 64 + wave * 16;
    const u16* mbp = mb + ((size_t)b * 1024 + q0 + l16) * 1024;

    bf16x8 qf0 = *(const bf16x8*)(qp + (size_t)(q0 + l16) * 64 + quad * 8);
    bf16x8 qf1 = *(const bf16x8*)(qp + (size_t)(q0 + l16) * 64 + 32 + quad * 8);

    f32x4 oacc[4] = {};
    float lsum = 0.f;
    u16* pw = &Psm[wave * 16 * 72];

    // per-lane fragment base pointers (fragment layout == global layout)
    //  K frag (S-phase B-op... A-op): row = kb + nt*16 + l16, a = quad*8 (+32)
    const u16* kfp = kp + (size_t)l16 * 64 + quad * 8;
    //  V frag (PV B-op): a-row = at*16 + l16, k = kb + hs*32 + quad*8
    const u16* vfp = vp + (size_t)l16 * 1024 + quad * 8;

    for (int kb = 0; kb < 1024; kb += 64) {
        // mask + ksum operands (mask: 8B/lane; ksum: quad-uniform 16B bcast)
        bf16x4 mraw[4];
        f32x4 k4[4];
#pragma unroll
        for (int nt = 0; nt < 4; nt++)
            mraw[nt] = *(const bf16x4*)(mbp + kb + nt * 16 + quad * 4);
#pragma unroll
        for (int nt = 0; nt < 4; nt++)
            k4[nt] = *(const f32x4*)(ksp + kb + nt * 16 + quad * 4);

        // S^T = K.Q^T, accumulator pre-biased with exp2-domain offset
        f32x4 sacc[4];
#pragma unroll
        for (int nt = 0; nt < 4; nt++)
            sacc[nt] = f32x4{SOFT_OFF, SOFT_OFF, SOFT_OFF, SOFT_OFF};
#pragma unroll
        for (int nt = 0; nt < 4; nt++) {
            const u16* kr = kfp + (size_t)(kb + nt * 16) * 64;
            bf16x8 kf0 = *(const bf16x8*)(kr);
            bf16x8 kf1 = *(const bf16x8*)(kr + 32);
            sacc[nt] = MFMA(kf0, qf0, sacc[nt]);
            sacc[nt] = MFMA(kf1, qf1, sacc[nt]);
        }

        // p = unmasked ? exp2(s + bias*ksum + off) : 0 ; packed bf16 P write
#pragma unroll
        for (int nt = 0; nt < 4; nt++) {
            float p[4];
#pragma unroll
            for (int r = 0; r < 4; r++) {
                float f = bf2f((u16)mraw[nt][r]);
                float x = fmaf(f, k4[nt][r], sacc[nt][r]);
                float e = fast_exp2(x);
                p[r] = (f > -1.0e29f) ? e : 0.f;
                lsum += p[r];
            }
            *(u32*)&pw[l16 * 72 + nt * 16 + quad * 4] = pack2bf(p[0], p[1]);
            *(u32*)&pw[l16 * 72 + nt * 16 + quad * 4 + 2] = pack2bf(p[2], p[3]);
        }

        // PV: O += P.V  (wave-private Psm round trip; DS ops in-order per
        // wave -> read sees the writes above, no barrier)
#pragma unroll
        for (int hs = 0; hs < 2; hs++) {
            bf16x8 pf = *(const bf16x8*)&pw[l16 * 72 + hs * 32 + quad * 8];
#pragma unroll
            for (int at = 0; at < 4; at++) {
                bf16x8 vf = *(const bf16x8*)(vfp + (size_t)(at * 16) * 1024 +
                                             kb + hs * 32);
                oacc[at] = MFMA(pf, vf, oacc[at]);
            }
        }
    }

    lsum += __shfl_xor(lsum, 16);
    lsum += __shfl_xor(lsum, 32);
    if (lane < 16) lsm[wave * 16 + lane] = lsum;
    // lsm region is wave-private; DS ops in-order per wave -> no barrier.

#pragma unroll
    for (int r = 0; r < 4; r++) {
        float linv = 1.0f / lsm[wave * 16 + quad * 4 + r];
        int q = q0 + quad * 4 + r;
#pragma unroll
        for (int at = 0; at < 4; at++) {
            ctx[(((size_t)b * 1024 + q) * 16 + h) * 64 + at * 16 + l16] =
                f2bf(oacc[at][r] * linv);
        }
    }
}

// ---------------------------------------------------------------------------
// gemmo: output projection, M=8192 N=1024 K=1024, f32 C. Same staging as gemm5.
// ---------------------------------------------------------------------------
__global__ __launch_bounds__(256) void gemmo(const u16* __restrict__ A,
                                             const u16* __restrict__ BT,
                                             float* __restrict__ C) {
    __shared__ u16 Asm[128 * 64];
    __shared__ u16 Bsm[128 * 64];
    int tid = threadIdx.x;
    int wave = tid >> 6, lane = tid & 63;
    int quad = lane >> 4, l16 = lane & 15;
    int wm = wave >> 1, wn = wave & 1;
    int mbase = blockIdx.y * 128, nbase = blockIdx.x * 128;
    f32x4 acc[4][4] = {};
    int srow = wave * 32 + (lane >> 3);
    int schunk = (lane & 7) ^ (lane >> 3);
    const u16* gA = A + (size_t)(mbase + srow) * 1024 + schunk * 8;
    const u16* gB = BT + (size_t)(nbase + srow) * 1024 + schunk * 8;
    u16* lA = Asm + wave * 2048;
    u16* lB = Bsm + wave * 2048;
    int sx = l16 & 7;
    for (int k0 = 0; k0 < 1024; k0 += 64) {
        __syncthreads();
#pragma unroll
        for (int j = 0; j < 4; j++) GLDS16(gA + k0 + j * 8192, lA + j * 512);
#pragma unroll
        for (int j = 0; j < 4; j++) GLDS16(gB + k0 + j * 8192, lB + j * 512);
        __syncthreads();
#pragma unroll
        for (int kk = 0; kk < 2; kk++) {
            bf16x8 af[4], bfr[4];
#pragma unroll
            for (int mt = 0; mt < 4; mt++)
                af[mt] = *(const bf16x8*)&Asm[(wm * 64 + mt * 16 + l16) * 64 +
                                              ((kk * 4 + quad) ^ sx) * 8];
#pragma unroll
            for (int nt = 0; nt < 4; nt++)
                bfr[nt] = *(const bf16x8*)&Bsm[(wn * 64 + nt * 16 + l16) * 64 +
                                               ((kk * 4 + quad) ^ sx) * 8];
#pragma unroll
            for (int mt = 0; mt < 4; mt++)
#pragma unroll
                for (int nt = 0; nt < 4; nt++)
                    acc[mt][nt] = MFMA(af[mt], bfr[nt], acc[mt][nt]);
        }
    }
#pragma unroll
    for (int mt = 0; mt < 4; mt++)
#pragma unroll
        for (int nt = 0; nt < 4; nt++)
#pragma unroll
            for (int r = 0; r < 4; r++) {
                int gm = mbase + wm * 64 + mt * 16 + quad * 4 + r;
                int gn = nbase + wn * 64 + nt * 16 + l16;
                C[(size_t)gm * 1024 + gn] = acc[mt][nt][r];
            }
}

// ---------------------------------------------------------------------------
extern "C" void kernel_launch(void* const* d_in, const int* in_sizes, int n_in,
                              void* d_out, int out_size, void* d_ws, size_t ws_size,
                              hipStream_t stream) {
    const float* states = (const float*)d_in[0];
    const float* key_states = (const float*)d_in[1];
    const float* masks = (const float*)d_in[2];
    const int* abias = (const int*)d_in[3];
    const float* Wq = (const float*)d_in[4];
    const float* Wk = (const float*)d_in[5];
    const float* Wv = (const float*)d_in[6];
    const float* Wout = (const float*)d_in[7];
    const float* be = (const float*)d_in[8];
    const float* bsc = (const float*)d_in[9];

    char* ws = (char*)d_ws;
    size_t off = 0;
    auto alloc = [&](size_t n) { void* p = ws + off; off += (n + 255) & ~(size_t)255; return p; };
    u16* wT = (u16*)alloc(4ull * 1024 * 1024 * 2);          // [Wq|Wk|Wv|Wout]^T bf16 (8 MB)
    u16* sbf = (u16*)alloc((size_t)BB * TT * DD * 2);       // states bf16 (16 MB)
    u16* kbf = (u16*)alloc((size_t)BB * TT * DD * 2);       // key_states bf16 (16 MB)
    u16* qb_ = (u16*)alloc((size_t)BB * HH * TT * AA * 2);  // q [B,H,T,A] (16 MB)
    u16* kb_ = (u16*)alloc((size_t)BB * HH * TT * AA * 2);  // k [B,H,T,A] (16 MB)
    u16* vT_ = (u16*)alloc((size_t)BB * HH * AA * TT * 2);  // vT [B,H,A,T] (16 MB)
    float* ks_ = (float*)alloc((size_t)BB * HH * TT * 4);   // ksum (0.5 MB)
    u16* mb_ = (u16*)alloc((size_t)BB * TT * TT * 2);       // fused mask+bias bf16 (16 MB)

    u16* woT = wT + 3145728;
    int* idx_ = (int*)qb_;   // 32 MB over qb_+kb_ (contiguous, dead until gemm5)
    u16* ctx_ = sbf;         // sbf dead after Q projection

    // 1) fused prep: cvt x2 + mbinit + idx init + tr_w  (all independent)
    prep1<<<dim3(17408), 256, 0, stream>>>(states, key_states, masks, Wq, Wk, Wv,
                                           Wout, sbf, kbf, mb_, idx_, wT);
    // 2) deterministic scatter (last-edge-wins, masked cells excluded)
    scat_max<<<dim3(EE / 256), 256, 0, stream>>>(abias, idx_);
    scat_res<<<dim3(EE / 256), 256, 0, stream>>>(abias, idx_, be, bsc, mb_);
    // 3) fused QKV projection (+ksum epilogue, +V-transpose epilogue)
    gemm5<<<dim3(24, 64), 256, 0, stream>>>(sbf, kbf, wT, qb_, kb_, vT_, ks_);
    // 4) attention (64-q tile, zero-staging barrier-free)
    attn6<<<dim3(16, 16, 8), 256, 0, stream>>>(qb_, kb_, vT_, ks_, mb_, ctx_);
    // 5) output projection -> d_out (f32)
    gemmo<<<dim3(8, 64), 256, 0, stream>>>(ctx_, woT, (float*)d_out);
}

// Round 4
// 386.522 us; speedup vs baseline: 1.4997x; 1.4997x over previous
//
#include <hip/hip_runtime.h>
#include <hip/hip_bf16.h>

// Problem dims (fixed)
#define BB 8
#define TT 1024
#define DD 1024
#define HH 16
#define AA 64
#define EE 262144

typedef unsigned short u16;
typedef unsigned int u32;
typedef short bf16x4 __attribute__((ext_vector_type(4)));
typedef short bf16x8 __attribute__((ext_vector_type(8)));
typedef float f32x4 __attribute__((ext_vector_type(4)));
typedef u32 u32x2 __attribute__((ext_vector_type(2)));

__device__ __forceinline__ float bf2f(u16 u) {
    union { float f; u32 i; } c; c.i = ((u32)u) << 16; return c.f;
}
__device__ __forceinline__ u16 f2bf(float f) {
    union { float f; u32 i; } c; c.f = f;
    u32 x = c.i;
    return (u16)((x + 0x7FFFu + ((x >> 16) & 1u)) >> 16);
}
// packed 2xf32 -> 2xbf16 (v_cvt_pk_bf16_f32 on gfx950)
__device__ __forceinline__ u32 pack2bf(float a, float b) {
    union { __hip_bfloat162 h; u32 u; } c;
    c.h = __float22bfloat162_rn(float2{a, b});
    return c.u;
}
// native exp2 (v_exp_f32)
__device__ __forceinline__ float fast_exp2(float x) {
#if __has_builtin(__builtin_amdgcn_exp2f)
    return __builtin_amdgcn_exp2f(x);
#else
    float r;
    asm("v_exp_f32 %0, %1" : "=v"(r) : "v"(x));
    return r;
#endif
}

// log2(e) folded scales: softmax computed as exp2( log2e * (s/8 + bias*ksum/8 - 20) )
#define QSCALE 0.18033688f          // 0.125 * 1.44269504
#define SOFT_OFF -28.8539008f       // -20 * 1.44269504

// async 16B global->LDS (per-lane gptr; LDS dest = wave-uniform base + lane*16)
#define GLDS16(gp, lp)                                                        \
    __builtin_amdgcn_global_load_lds(                                         \
        (const __attribute__((address_space(1))) u32*)(const void*)(gp),      \
        (__attribute__((address_space(3))) u32*)(void*)(lp), 16, 0, 0)

#define MFMA(a, b, c) __builtin_amdgcn_mfma_f32_16x16x32_bf16((a), (b), (c), 0, 0, 0)

// ---------------------------------------------------------------------------
// prep1: fused independent prep work, partitioned by blockIdx.x
//  [0,4096)      cvt states -> sbf
//  [4096,8192)   cvt key_states -> kbf
//  [8192,12288)  mbinit (masks -> bf16 mb)
//  [12288,16384) idx init (-1)
//  [16384,17408) tr_w (4x 1024x1024 f32 -> bf16 transposed)
// ---------------------------------------------------------------------------
__global__ __launch_bounds__(256) void prep1(const float* __restrict__ states,
                                             const float* __restrict__ keys,
                                             const float* __restrict__ masks,
                                             const float* __restrict__ Wq,
                                             const float* __restrict__ Wk,
                                             const float* __restrict__ Wv,
                                             const float* __restrict__ Wout,
                                             u16* __restrict__ sbf,
                                             u16* __restrict__ kbf,
                                             u16* __restrict__ mb,
                                             int* __restrict__ idx,
                                             u16* __restrict__ wT) {
    __shared__ u16 t[64 * 72];
    int bi = blockIdx.x, tid = threadIdx.x;
    if (bi < 12288) {
        if (bi < 8192) {  // cvt
            const float* src = (bi < 4096) ? states : keys;
            u16* dst = (bi < 4096) ? sbf : kbf;
            size_t i = ((size_t)(bi & 4095) * 256 + tid) * 8;
            f32x4 a = *(const f32x4*)(src + i);
            f32x4 b = *(const f32x4*)(src + i + 4);
            u32 o[4];
            o[0] = pack2bf(a[0], a[1]);
            o[1] = pack2bf(a[2], a[3]);
            o[2] = pack2bf(b[0], b[1]);
            o[3] = pack2bf(b[2], b[3]);
            *(bf16x8*)(dst + i) = *(bf16x8*)o;
        } else {  // mbinit
            size_t i = ((size_t)(bi - 8192) * 256 + tid) * 8;
            f32x4 a = *(const f32x4*)(masks + i);
            f32x4 b = *(const f32x4*)(masks + i + 4);
            const u16 M = f2bf(-1.0e30f);
            bf16x8 o;
#pragma unroll
            for (int j = 0; j < 4; j++) {
                o[j] = (short)((a[j] != 0.f) ? M : 0);
                o[4 + j] = (short)((b[j] != 0.f) ? M : 0);
            }
            *(bf16x8*)(mb + i) = o;
        }
    } else if (bi < 16384) {  // idx init
        size_t i = ((size_t)(bi - 12288) * 256 + tid) * 8;
        int4 m1 = {-1, -1, -1, -1};
        *(int4*)(idx + i) = m1;
        *(int4*)(idx + i + 4) = m1;
    } else {  // tr_w
        int zb = bi - 16384;
        int z = zb >> 8, by = (zb >> 4) & 15, bx = zb & 15;
        const float* src = (z == 0) ? Wq : (z == 1) ? Wk : (z == 2) ? Wv : Wout;
        u16* dst = wT + (size_t)z * 1048576;
        int row0 = by * 64, col0 = bx * 64;
        int r = tid >> 2, c0 = (tid & 3) * 16;
        const float* sp = src + (size_t)(row0 + r) * 1024 + col0 + c0;
        f32x4 f0 = *(const f32x4*)(sp);
        f32x4 f1 = *(const f32x4*)(sp + 4);
        f32x4 f2_ = *(const f32x4*)(sp + 8);
        f32x4 f3 = *(const f32x4*)(sp + 12);
#pragma unroll
        for (int j = 0; j < 4; j++) {
            t[r * 72 + c0 + j] = f2bf(f0[j]);
            t[r * 72 + c0 + 4 + j] = f2bf(f1[j]);
            t[r * 72 + c0 + 8 + j] = f2bf(f2_[j]);
            t[r * 72 + c0 + 12 + j] = f2bf(f3[j]);
        }
        __syncthreads();
        bf16x8 o0, o1;
#pragma unroll
        for (int j = 0; j < 8; j++) o0[j] = (short)t[(c0 + j) * 72 + r];
#pragma unroll
        for (int j = 0; j < 8; j++) o1[j] = (short)t[(c0 + 8 + j) * 72 + r];
        *(bf16x8*)(dst + (size_t)(col0 + r) * 1024 + row0 + c0) = o0;
        *(bf16x8*)(dst + (size_t)(col0 + r) * 1024 + row0 + c0 + 8) = o1;
    }
}

// ---------------------------------------------------------------------------
// scatter pass 1 — last edge index wins (numpy semantics)
// ---------------------------------------------------------------------------
__global__ __launch_bounds__(256) void scat_max(const int* __restrict__ ab,
                                                int* __restrict__ idx) {
    int e = blockIdx.x * 256 + threadIdx.x;
    int4 rec = ((const int4*)ab)[e];
    atomicMax(&idx[((((size_t)rec.y << 10) + rec.z) << 10) + rec.w], e);
}

// scatter pass 2 — winner writes prescaled bf16 value (skip masked cells)
// proj prescaled by 0.125 * log2(e) to match exp2-based softmax.
__global__ __launch_bounds__(256) void scat_res(const int* __restrict__ ab,
                                                const int* __restrict__ idx,
                                                const float* __restrict__ be,
                                                const float* __restrict__ bsc,
                                                u16* __restrict__ mb) {
    __shared__ float proj[32];
    int tid = threadIdx.x;
    if (tid < 32) {
        float s = 0.f;
        for (int a = 0; a < 64; a++) s += be[tid * 64 + a] * bsc[a];
        proj[tid] = s * QSCALE;  // fold 1/sqrt(A) * log2(e)
    }
    __syncthreads();
    int e = blockIdx.x * 256 + tid;
    int4 rec = ((const int4*)ab)[e];
    size_t cell = ((((size_t)rec.y << 10) + rec.z) << 10) + rec.w;
    if (idx[cell] == e && bf2f(mb[cell]) > -1.0e29f) mb[cell] = f2bf(proj[rec.x]);
}

// ---------------------------------------------------------------------------
// gemm5: fused QKV projection. grid (24,64): mat = x>>3 (0=Q,1=K,2=V).
// 128x128 tile, BK=64, both operands via global_load_lds w/ global-side XOR
// chunk swizzle (conflict-free unpadded LDS reads).
// mat 0: qb [B,H,T,A] bf16, scaled 0.125*log2e (exp2 softmax).
// mat 1: kb [B,H,T,A] bf16 + ksum f32 (shuffle-reduced in epilogue).
// mat 2: vT [B,H,A,T] bf16 via LDS transpose epilogue.
// ---------------------------------------------------------------------------
__global__ __launch_bounds__(256) void gemm5(const u16* __restrict__ sbf,
                                             const u16* __restrict__ kbf,
                                             const u16* __restrict__ wT,
                                             u16* __restrict__ qb,
                                             u16* __restrict__ kb,
                                             u16* __restrict__ vT,
                                             float* __restrict__ ks) {
    __shared__ u16 smem[17408];  // 34816 B: staging [0,16384) u16, transpose 128x136
    int tid = threadIdx.x;
    int wave = tid >> 6, lane = tid & 63;
    int quad = lane >> 4, l16 = lane & 15;
    int wm = wave >> 1, wn = wave & 1;
    int mat = blockIdx.x >> 3;
    int nloc = (blockIdx.x & 7) * 128;
    int mbase = blockIdx.y * 128;
    const u16* A = (mat == 0) ? sbf : kbf;
    const u16* BT = wT + (size_t)mat * 1048576;
    u16* Asm = smem;
    u16* Bsm = smem + 8192;
    f32x4 acc[4][4] = {};
    int srow = wave * 32 + (lane >> 3);
    int schunk = (lane & 7) ^ (lane >> 3);
    const u16* gA = A + (size_t)(mbase + srow) * 1024 + schunk * 8;
    const u16* gB = BT + (size_t)(nloc + srow) * 1024 + schunk * 8;
    u16* lA = Asm + wave * 2048;
    u16* lB = Bsm + wave * 2048;
    int sx = l16 & 7;
    for (int k0 = 0; k0 < 1024; k0 += 64) {
        __syncthreads();
#pragma unroll
        for (int j = 0; j < 4; j++) GLDS16(gA + k0 + j * 8192, lA + j * 512);
#pragma unroll
        for (int j = 0; j < 4; j++) GLDS16(gB + k0 + j * 8192, lB + j * 512);
        __syncthreads();
#pragma unroll
        for (int kk = 0; kk < 2; kk++) {
            bf16x8 af[4], bfr[4];
#pragma unroll
            for (int mt = 0; mt < 4; mt++)
                af[mt] = *(const bf16x8*)&Asm[(wm * 64 + mt * 16 + l16) * 64 +
                                              ((kk * 4 + quad) ^ sx) * 8];
#pragma unroll
            for (int nt = 0; nt < 4; nt++)
                bfr[nt] = *(const bf16x8*)&Bsm[(wn * 64 + nt * 16 + l16) * 64 +
                                               ((kk * 4 + quad) ^ sx) * 8];
#pragma unroll
            for (int mt = 0; mt < 4; mt++)
#pragma unroll
                for (int nt = 0; nt < 4; nt++)
                    acc[mt][nt] = MFMA(af[mt], bfr[nt], acc[mt][nt]);
        }
    }

    if (mat == 2) {
        // V: transpose through LDS -> vT [B,H,A,T]
        __syncthreads();  // all waves done with staging LDS
#pragma unroll
        for (int mt = 0; mt < 4; mt++)
#pragma unroll
            for (int nt = 0; nt < 4; nt++)
#pragma unroll
                for (int r = 0; r < 4; r++) {
                    int rowl = wm * 64 + mt * 16 + quad * 4 + r;
                    int coll = wn * 64 + nt * 16 + l16;
                    smem[coll * 136 + rowl] = f2bf(acc[mt][nt][r]);
                }
        __syncthreads();
        int b = mbase >> 10, t0 = mbase & 1023;
        int c = tid >> 1, hf = tid & 1;
        int h = (nloc >> 6) + (c >> 6);
        int a = c & 63;
        u16* dst = vT + ((((size_t)(b * 16 + h)) * 64 + a) << 10) + t0 + hf * 64;
        const u16* srcl = smem + c * 136 + hf * 64;
#pragma unroll
        for (int j = 0; j < 8; j++) *(bf16x8*)(dst + j * 8) = *(const bf16x8*)(srcl + j * 8);
    } else {
        u16* dst = (mat == 0) ? qb : kb;
        float sc = (mat == 0) ? QSCALE : 1.0f;
#pragma unroll
        for (int mt = 0; mt < 4; mt++)
#pragma unroll
            for (int nt = 0; nt < 4; nt++)
#pragma unroll
                for (int r = 0; r < 4; r++) {
                    int gm = mbase + wm * 64 + mt * 16 + quad * 4 + r;
                    int gnl = nloc + wn * 64 + nt * 16 + l16;
                    int b = gm >> 10, t = gm & 1023, h = gnl >> 6, a = gnl & 63;
                    dst[(((size_t)(b * 16 + h) * 1024) + t) * 64 + a] =
                        f2bf(acc[mt][nt][r] * sc);
                }
        if (mat == 1) {
            // ksum[b,h,t] = sum_a K (f32 acc, pre-rounding)
            int h = (nloc + wn * 64) >> 6;
#pragma unroll
            for (int mt = 0; mt < 4; mt++)
#pragma unroll
                for (int r = 0; r < 4; r++) {
                    float s = acc[mt][0][r] + acc[mt][1][r] + acc[mt][2][r] + acc[mt][3][r];
                    s += __shfl_xor(s, 1);
                    s += __shfl_xor(s, 2);
                    s += __shfl_xor(s, 4);
                    s += __shfl_xor(s, 8);
                    if (l16 == 0) {
                        int gm = mbase + wm * 64 + mt * 16 + quad * 4 + r;
                        int b = gm >> 10, t = gm & 1023;
                        ks[(((size_t)(b * 16 + h)) << 10) + t] = s;
                    }
                }
        }
    }
}

// ---------------------------------------------------------------------------
// attn7: attn4 skeleton (single-buffered GLDS staging, 2x __syncthreads per
// k-block — empirically the best structure: R2 dbuf lost occupancy, R3
// zero-staging serialized on VMEM latency). VALU diet on top:
//  - exp2-domain softmax (scales pre-folded; removes x*log2e mul)
//  - row-sum via MFMA ones-trick: lacc = MFMA(pf, ONES, lacc) -> deletes
//    16 v_add/iter + epilogue shuffles + lsm (and is numerically consistent
//    with the bf16 P used in PV)
//  - P writes as single ds_write_b64 per nt (4 instead of 8 DS writes/iter)
//  - ksum via direct quad-uniform f32x4 global loads (drop sksm staging)
// ---------------------------------------------------------------------------
__global__ __launch_bounds__(256) void attn7(const u16* __restrict__ qbuf,
                                             const u16* __restrict__ kbuf,
                                             const u16* __restrict__ vT,
                                             const float* __restrict__ ksum,
                                             const u16* __restrict__ mb,
                                             u16* __restrict__ ctx) {
    __shared__ u16 Ksm[64 * 64];
    __shared__ u16 Vsm[64 * 64];
    __shared__ u16 Psm[4 * 16 * 72];
    int tid = threadIdx.x;
    int wave = tid >> 6, lane = tid & 63;
    int quad = lane >> 4, l16 = lane & 15;
    int qb = blockIdx.x, h = blockIdx.y, b = blockIdx.z;
    int bh = b * 16 + h;
    const u16* qp = qbuf + (size_t)bh * 65536;
    const u16* kp = kbuf + (size_t)bh * 65536;
    const u16* vp = vT + (size_t)bh * 65536;
    const float* ksp = ksum + (size_t)bh * 1024;
    int q0 = qb * 64 + wave * 16;
    const u16* mbp = mb + ((size_t)b * 1024 + q0 + l16) * 1024;

    bf16x8 qf0 = *(const bf16x8*)(qp + (size_t)(q0 + l16) * 64 + quad * 8);
    bf16x8 qf1 = *(const bf16x8*)(qp + (size_t)(q0 + l16) * 64 + 32 + quad * 8);

    // ones B-fragment for the MFMA row-sum (every element bf16 1.0)
    bf16x8 ONES;
#pragma unroll
    for (int j = 0; j < 8; j++) ONES[j] = (short)0x3F80;

    f32x4 oacc[4] = {};
    f32x4 lacc = {};
    // staging geometry: lane -> row octet (lane>>3), swizzled chunk
    int r8 = lane >> 3;
    int sch = (lane & 7) ^ r8;
    u16* lK = Ksm + wave * 1024;
    u16* lV = Vsm + wave * 1024;
    const u16* gK0 = kp + (size_t)(wave * 16 + r8) * 64 + sch * 8;
    const u16* gV0 = vp + (size_t)(wave * 16 + r8) * 1024 + sch * 8;
    int sx = l16 & 7;
    u16* pw = &Psm[wave * 16 * 72];

    for (int kb = 0; kb < 1024; kb += 64) {
        bf16x4 mraw[4];
        f32x4 k4[4];
#pragma unroll
        for (int nt = 0; nt < 4; nt++)
            mraw[nt] = *(const bf16x4*)(mbp + kb + nt * 16 + quad * 4);
#pragma unroll
        for (int nt = 0; nt < 4; nt++)
            k4[nt] = *(const f32x4*)(ksp + kb + nt * 16 + quad * 4);
        __syncthreads();  // prev-iter LDS reads done
        GLDS16(gK0 + (size_t)kb * 64, lK);
        GLDS16(gK0 + (size_t)(kb + 8) * 64, lK + 512);
        GLDS16(gV0 + kb, lV);
        GLDS16(gV0 + 8 * 1024 + kb, lV + 512);
        __syncthreads();  // staging visible

        // S^T = K.Q^T, accumulator pre-biased with exp2-domain offset
        f32x4 sacc[4];
#pragma unroll
        for (int nt = 0; nt < 4; nt++)
            sacc[nt] = f32x4{SOFT_OFF, SOFT_OFF, SOFT_OFF, SOFT_OFF};
#pragma unroll
        for (int nt = 0; nt < 4; nt++) {
            bf16x8 kf0 = *(const bf16x8*)&Ksm[(nt * 16 + l16) * 64 + (quad ^ sx) * 8];
            bf16x8 kf1 = *(const bf16x8*)&Ksm[(nt * 16 + l16) * 64 + ((4 + quad) ^ sx) * 8];
            sacc[nt] = MFMA(kf0, qf0, sacc[nt]);
            sacc[nt] = MFMA(kf1, qf1, sacc[nt]);
        }

        // p = unmasked ? exp2(s + bias*ksum + off) : 0 ; packed bf16 P write
#pragma unroll
        for (int nt = 0; nt < 4; nt++) {
            float p[4];
#pragma unroll
            for (int r = 0; r < 4; r++) {
                float f = bf2f((u16)mraw[nt][r]);
                float x = fmaf(f, k4[nt][r], sacc[nt][r]);
                float e = fast_exp2(x);
                p[r] = (f > -1.0e29f) ? e : 0.f;
            }
            u32x2 pk;
            pk[0] = pack2bf(p[0], p[1]);
            pk[1] = pack2bf(p[2], p[3]);
            *(u32x2*)&pw[l16 * 72 + nt * 16 + quad * 4] = pk;
        }

        // PV: O += P.V ; row-sum via ones-MFMA (wave-private Psm round trip;
        // DS ops in-order per wave)
#pragma unroll
        for (int hs = 0; hs < 2; hs++) {
            bf16x8 pf = *(const bf16x8*)&pw[l16 * 72 + hs * 32 + quad * 8];
            lacc = MFMA(pf, ONES, lacc);
#pragma unroll
            for (int at = 0; at < 4; at++) {
                bf16x8 vf = *(const bf16x8*)&Vsm[(at * 16 + l16) * 64 +
                                                 ((hs * 4 + quad) ^ sx) * 8];
                oacc[at] = MFMA(pf, vf, oacc[at]);
            }
        }
    }

    // lacc[r] = full row sum for q = q0 + quad*4 + r (all l16 cols identical)
#pragma unroll
    for (int r = 0; r < 4; r++) {
        float linv = 1.0f / lacc[r];
        int q = q0 + quad * 4 + r;
#pragma unroll
        for (int at = 0; at < 4; at++) {
            ctx[(((size_t)b * 1024 + q) * 16 + h) * 64 + at * 16 + l16] =
                f2bf(oacc[at][r] * linv);
        }
    }
}

// ---------------------------------------------------------------------------
// gemmo: output projection, M=8192 N=1024 K=1024, f32 C. Same staging as gemm5.
// ---------------------------------------------------------------------------
__global__ __launch_bounds__(256) void gemmo(const u16* __restrict__ A,
                                             const u16* __restrict__ BT,
                                             float* __restrict__ C) {
    __shared__ u16 Asm[128 * 64];
    __shared__ u16 Bsm[128 * 64];
    int tid = threadIdx.x;
    int wave = tid >> 6, lane = tid & 63;
    int quad = lane >> 4, l16 = lane & 15;
    int wm = wave >> 1, wn = wave & 1;
    int mbase = blockIdx.y * 128, nbase = blockIdx.x * 128;
    f32x4 acc[4][4] = {};
    int srow = wave * 32 + (lane >> 3);
    int schunk = (lane & 7) ^ (lane >> 3);
    const u16* gA = A + (size_t)(mbase + srow) * 1024 + schunk * 8;
    const u16* gB = BT + (size_t)(nbase + srow) * 1024 + schunk * 8;
    u16* lA = Asm + wave * 2048;
    u16* lB = Bsm + wave * 2048;
    int sx = l16 & 7;
    for (int k0 = 0; k0 < 1024; k0 += 64) {
        __syncthreads();
#pragma unroll
        for (int j = 0; j < 4; j++) GLDS16(gA + k0 + j * 8192, lA + j * 512);
#pragma unroll
        for (int j = 0; j < 4; j++) GLDS16(gB + k0 + j * 8192, lB + j * 512);
        __syncthreads();
#pragma unroll
        for (int kk = 0; kk < 2; kk++) {
            bf16x8 af[4], bfr[4];
#pragma unroll
            for (int mt = 0; mt < 4; mt++)
                af[mt] = *(const bf16x8*)&Asm[(wm * 64 + mt * 16 + l16) * 64 +
                                              ((kk * 4 + quad) ^ sx) * 8];
#pragma unroll
            for (int nt = 0; nt < 4; nt++)
                bfr[nt] = *(const bf16x8*)&Bsm[(wn * 64 + nt * 16 + l16) * 64 +
                                               ((kk * 4 + quad) ^ sx) * 8];
#pragma unroll
            for (int mt = 0; mt < 4; mt++)
#pragma unroll
                for (int nt = 0; nt < 4; nt++)
                    acc[mt][nt] = MFMA(af[mt], bfr[nt], acc[mt][nt]);
        }
    }
#pragma unroll
    for (int mt = 0; mt < 4; mt++)
#pragma unroll
        for (int nt = 0; nt < 4; nt++)
#pragma unroll
            for (int r = 0; r < 4; r++) {
                int gm = mbase + wm * 64 + mt * 16 + quad * 4 + r;
                int gn = nbase + wn * 64 + nt * 16 + l16;
                C[(size_t)gm * 1024 + gn] = acc[mt][nt][r];
            }
}

// ---------------------------------------------------------------------------
extern "C" void kernel_launch(void* const* d_in, const int* in_sizes, int n_in,
                              void* d_out, int out_size, void* d_ws, size_t ws_size,
                              hipStream_t stream) {
    const float* states = (const float*)d_in[0];
    const float* key_states = (const float*)d_in[1];
    const float* masks = (const float*)d_in[2];
    const int* abias = (const int*)d_in[3];
    const float* Wq = (const float*)d_in[4];
    const float* Wk = (const float*)d_in[5];
    const float* Wv = (const float*)d_in[6];
    const float* Wout = (const float*)d_in[7];
    const float* be = (const float*)d_in[8];
    const float* bsc = (const float*)d_in[9];

    char* ws = (char*)d_ws;
    size_t off = 0;
    auto alloc = [&](size_t n) { void* p = ws + off; off += (n + 255) & ~(size_t)255; return p; };
    u16* wT = (u16*)alloc(4ull * 1024 * 1024 * 2);          // [Wq|Wk|Wv|Wout]^T bf16 (8 MB)
    u16* sbf = (u16*)alloc((size_t)BB * TT * DD * 2);       // states bf16 (16 MB)
    u16* kbf = (u16*)alloc((size_t)BB * TT * DD * 2);       // key_states bf16 (16 MB)
    u16* qb_ = (u16*)alloc((size_t)BB * HH * TT * AA * 2);  // q [B,H,T,A] (16 MB)
    u16* kb_ = (u16*)alloc((size_t)BB * HH * TT * AA * 2);  // k [B,H,T,A] (16 MB)
    u16* vT_ = (u16*)alloc((size_t)BB * HH * AA * TT * 2);  // vT [B,H,A,T] (16 MB)
    float* ks_ = (float*)alloc((size_t)BB * HH * TT * 4);   // ksum (0.5 MB)
    u16* mb_ = (u16*)alloc((size_t)BB * TT * TT * 2);       // fused mask+bias bf16 (16 MB)

    u16* woT = wT + 3145728;
    int* idx_ = (int*)qb_;   // 32 MB over qb_+kb_ (contiguous, dead until gemm5)
    u16* ctx_ = sbf;         // sbf dead after Q projection

    // 1) fused prep: cvt x2 + mbinit + idx init + tr_w  (all independent)
    prep1<<<dim3(17408), 256, 0, stream>>>(states, key_states, masks, Wq, Wk, Wv,
                                           Wout, sbf, kbf, mb_, idx_, wT);
    // 2) deterministic scatter (last-edge-wins, masked cells excluded)
    scat_max<<<dim3(EE / 256), 256, 0, stream>>>(abias, idx_);
    scat_res<<<dim3(EE / 256), 256, 0, stream>>>(abias, idx_, be, bsc, mb_);
    // 3) fused QKV projection (+ksum epilogue, +V-transpose epilogue)
    gemm5<<<dim3(24, 64), 256, 0, stream>>>(sbf, kbf, wT, qb_, kb_, vT_, ks_);
    // 4) attention (attn4 skeleton + VALU diet)
    attn7<<<dim3(16, 16, 8), 256, 0, stream>>>(qb_, kb_, vT_, ks_, mb_, ctx_);
    // 5) output projection -> d_out (f32)
    gemmo<<<dim3(8, 64), 256, 0, stream>>>(ctx_, woT, (float*)d_out);
}

// Round 5
// 362.335 us; speedup vs baseline: 1.5998x; 1.0668x over previous
//
#include <hip/hip_runtime.h>
#include <hip/hip_bf16.h>

// Problem dims (fixed)
#define BB 8
#define TT 1024
#define DD 1024
#define HH 16
#define AA 64
#define EE 262144

typedef unsigned short u16;
typedef unsigned int u32;
typedef short bf16x4 __attribute__((ext_vector_type(4)));
typedef short bf16x8 __attribute__((ext_vector_type(8)));
typedef float f32x4 __attribute__((ext_vector_type(4)));

__device__ __forceinline__ float bf2f(u16 u) {
    union { float f; u32 i; } c; c.i = ((u32)u) << 16; return c.f;
}
__device__ __forceinline__ u16 f2bf(float f) {
    union { float f; u32 i; } c; c.f = f;
    u32 x = c.i;
    return (u16)((x + 0x7FFFu + ((x >> 16) & 1u)) >> 16);
}
// packed 2xf32 -> 2xbf16 (v_cvt_pk_bf16_f32 on gfx950)
__device__ __forceinline__ u32 pack2bf(float a, float b) {
    union { __hip_bfloat162 h; u32 u; } c;
    c.h = __float22bfloat162_rn(float2{a, b});
    return c.u;
}
// native exp2 (v_exp_f32)
__device__ __forceinline__ float fast_exp2(float x) {
#if __has_builtin(__builtin_amdgcn_exp2f)
    return __builtin_amdgcn_exp2f(x);
#else
    float r;
    asm("v_exp_f32 %0, %1" : "=v"(r) : "v"(x));
    return r;
#endif
}

// log2(e) folded scales: softmax computed as exp2( log2e * (s/8 + bias*ksum/8 - 20) )
#define QSCALE 0.18033688f          // 0.125 * 1.44269504
#define SOFT_OFF -28.8539008f       // -20 * 1.44269504

// async 16B global->LDS (per-lane gptr; LDS dest = wave-uniform base + lane*16)
#define GLDS16(gp, lp)                                                        \
    __builtin_amdgcn_global_load_lds(                                         \
        (const __attribute__((address_space(1))) u32*)(const void*)(gp),      \
        (__attribute__((address_space(3))) u32*)(void*)(lp), 16, 0, 0)

#define MFMA(a, b, c) __builtin_amdgcn_mfma_f32_16x16x32_bf16((a), (b), (c), 0, 0, 0)

// ---------------------------------------------------------------------------
// prep1: fused independent prep work, partitioned by blockIdx.x
//  [0,4096)      cvt states -> sbf
//  [4096,8192)   cvt key_states -> kbf
//  [8192,12288)  mbinit (masks -> bf16 mb)
//  [12288,16384) idx init (-1)
//  [16384,17408) tr_w (4x 1024x1024 f32 -> bf16 transposed)
// ---------------------------------------------------------------------------
__global__ __launch_bounds__(256) void prep1(const float* __restrict__ states,
                                             const float* __restrict__ keys,
                                             const float* __restrict__ masks,
                                             const float* __restrict__ Wq,
                                             const float* __restrict__ Wk,
                                             const float* __restrict__ Wv,
                                             const float* __restrict__ Wout,
                                             u16* __restrict__ sbf,
                                             u16* __restrict__ kbf,
                                             u16* __restrict__ mb,
                                             int* __restrict__ idx,
                                             u16* __restrict__ wT) {
    __shared__ u16 t[64 * 72];
    int bi = blockIdx.x, tid = threadIdx.x;
    if (bi < 12288) {
        if (bi < 8192) {  // cvt
            const float* src = (bi < 4096) ? states : keys;
            u16* dst = (bi < 4096) ? sbf : kbf;
            size_t i = ((size_t)(bi & 4095) * 256 + tid) * 8;
            f32x4 a = *(const f32x4*)(src + i);
            f32x4 b = *(const f32x4*)(src + i + 4);
            u32 o[4];
            o[0] = pack2bf(a[0], a[1]);
            o[1] = pack2bf(a[2], a[3]);
            o[2] = pack2bf(b[0], b[1]);
            o[3] = pack2bf(b[2], b[3]);
            *(bf16x8*)(dst + i) = *(bf16x8*)o;
        } else {  // mbinit
            size_t i = ((size_t)(bi - 8192) * 256 + tid) * 8;
            f32x4 a = *(const f32x4*)(masks + i);
            f32x4 b = *(const f32x4*)(masks + i + 4);
            const u16 M = f2bf(-1.0e30f);
            bf16x8 o;
#pragma unroll
            for (int j = 0; j < 4; j++) {
                o[j] = (short)((a[j] != 0.f) ? M : 0);
                o[4 + j] = (short)((b[j] != 0.f) ? M : 0);
            }
            *(bf16x8*)(mb + i) = o;
        }
    } else if (bi < 16384) {  // idx init
        size_t i = ((size_t)(bi - 12288) * 256 + tid) * 8;
        int4 m1 = {-1, -1, -1, -1};
        *(int4*)(idx + i) = m1;
        *(int4*)(idx + i + 4) = m1;
    } else {  // tr_w
        int zb = bi - 16384;
        int z = zb >> 8, by = (zb >> 4) & 15, bx = zb & 15;
        const float* src = (z == 0) ? Wq : (z == 1) ? Wk : (z == 2) ? Wv : Wout;
        u16* dst = wT + (size_t)z * 1048576;
        int row0 = by * 64, col0 = bx * 64;
        int r = tid >> 2, c0 = (tid & 3) * 16;
        const float* sp = src + (size_t)(row0 + r) * 1024 + col0 + c0;
        f32x4 f0 = *(const f32x4*)(sp);
        f32x4 f1 = *(const f32x4*)(sp + 4);
        f32x4 f2_ = *(const f32x4*)(sp + 8);
        f32x4 f3 = *(const f32x4*)(sp + 12);
#pragma unroll
        for (int j = 0; j < 4; j++) {
            t[r * 72 + c0 + j] = f2bf(f0[j]);
            t[r * 72 + c0 + 4 + j] = f2bf(f1[j]);
            t[r * 72 + c0 + 8 + j] = f2bf(f2_[j]);
            t[r * 72 + c0 + 12 + j] = f2bf(f3[j]);
        }
        __syncthreads();
        bf16x8 o0, o1;
#pragma unroll
        for (int j = 0; j < 8; j++) o0[j] = (short)t[(c0 + j) * 72 + r];
#pragma unroll
        for (int j = 0; j < 8; j++) o1[j] = (short)t[(c0 + 8 + j) * 72 + r];
        *(bf16x8*)(dst + (size_t)(col0 + r) * 1024 + row0 + c0) = o0;
        *(bf16x8*)(dst + (size_t)(col0 + r) * 1024 + row0 + c0 + 8) = o1;
    }
}

// ---------------------------------------------------------------------------
// scatter pass 1 — last edge index wins (numpy semantics)
// ---------------------------------------------------------------------------
__global__ __launch_bounds__(256) void scat_max(const int* __restrict__ ab,
                                                int* __restrict__ idx) {
    int e = blockIdx.x * 256 + threadIdx.x;
    int4 rec = ((const int4*)ab)[e];
    atomicMax(&idx[((((size_t)rec.y << 10) + rec.z) << 10) + rec.w], e);
}

// scatter pass 2 — winner writes prescaled bf16 value (skip masked cells)
// proj prescaled by 0.125 * log2(e) to match exp2-based softmax.
__global__ __launch_bounds__(256) void scat_res(const int* __restrict__ ab,
                                                const int* __restrict__ idx,
                                                const float* __restrict__ be,
                                                const float* __restrict__ bsc,
                                                u16* __restrict__ mb) {
    __shared__ float proj[32];
    int tid = threadIdx.x;
    if (tid < 32) {
        float s = 0.f;
        for (int a = 0; a < 64; a++) s += be[tid * 64 + a] * bsc[a];
        proj[tid] = s * QSCALE;  // fold 1/sqrt(A) * log2(e)
    }
    __syncthreads();
    int e = blockIdx.x * 256 + tid;
    int4 rec = ((const int4*)ab)[e];
    size_t cell = ((((size_t)rec.y << 10) + rec.z) << 10) + rec.w;
    if (idx[cell] == e && bf2f(mb[cell]) > -1.0e29f) mb[cell] = f2bf(proj[rec.x]);
}

// ---------------------------------------------------------------------------
// gemm5: fused QKV projection. grid (24,64): mat = x>>3 (0=Q,1=K,2=V).
// 128x128 tile, BK=64, both operands via global_load_lds w/ global-side XOR
// chunk swizzle (conflict-free unpadded LDS reads).
// mat 0: qb [B,H,T,A] bf16, scaled 0.125*log2e (exp2 softmax).
// mat 1: kb [B,H,T,A] bf16 + ksum f32 (shuffle-reduced in epilogue).
// mat 2: vT [B,H,A,T] bf16 via LDS transpose epilogue.
// ---------------------------------------------------------------------------
__global__ __launch_bounds__(256) void gemm5(const u16* __restrict__ sbf,
                                             const u16* __restrict__ kbf,
                                             const u16* __restrict__ wT,
                                             u16* __restrict__ qb,
                                             u16* __restrict__ kb,
                                             u16* __restrict__ vT,
                                             float* __restrict__ ks) {
    __shared__ u16 smem[17408];  // 34816 B: staging [0,16384) u16, transpose 128x136
    int tid = threadIdx.x;
    int wave = tid >> 6, lane = tid & 63;
    int quad = lane >> 4, l16 = lane & 15;
    int wm = wave >> 1, wn = wave & 1;
    int mat = blockIdx.x >> 3;
    int nloc = (blockIdx.x & 7) * 128;
    int mbase = blockIdx.y * 128;
    const u16* A = (mat == 0) ? sbf : kbf;
    const u16* BT = wT + (size_t)mat * 1048576;
    u16* Asm = smem;
    u16* Bsm = smem + 8192;
    f32x4 acc[4][4] = {};
    int srow = wave * 32 + (lane >> 3);
    int schunk = (lane & 7) ^ (lane >> 3);
    const u16* gA = A + (size_t)(mbase + srow) * 1024 + schunk * 8;
    const u16* gB = BT + (size_t)(nloc + srow) * 1024 + schunk * 8;
    u16* lA = Asm + wave * 2048;
    u16* lB = Bsm + wave * 2048;
    int sx = l16 & 7;
    for (int k0 = 0; k0 < 1024; k0 += 64) {
        __syncthreads();
#pragma unroll
        for (int j = 0; j < 4; j++) GLDS16(gA + k0 + j * 8192, lA + j * 512);
#pragma unroll
        for (int j = 0; j < 4; j++) GLDS16(gB + k0 + j * 8192, lB + j * 512);
        __syncthreads();
#pragma unroll
        for (int kk = 0; kk < 2; kk++) {
            bf16x8 af[4], bfr[4];
#pragma unroll
            for (int mt = 0; mt < 4; mt++)
                af[mt] = *(const bf16x8*)&Asm[(wm * 64 + mt * 16 + l16) * 64 +
                                              ((kk * 4 + quad) ^ sx) * 8];
#pragma unroll
            for (int nt = 0; nt < 4; nt++)
                bfr[nt] = *(const bf16x8*)&Bsm[(wn * 64 + nt * 16 + l16) * 64 +
                                               ((kk * 4 + quad) ^ sx) * 8];
#pragma unroll
            for (int mt = 0; mt < 4; mt++)
#pragma unroll
                for (int nt = 0; nt < 4; nt++)
                    acc[mt][nt] = MFMA(af[mt], bfr[nt], acc[mt][nt]);
        }
    }

    if (mat == 2) {
        // V: transpose through LDS -> vT [B,H,A,T]
        __syncthreads();  // all waves done with staging LDS
#pragma unroll
        for (int mt = 0; mt < 4; mt++)
#pragma unroll
            for (int nt = 0; nt < 4; nt++)
#pragma unroll
                for (int r = 0; r < 4; r++) {
                    int rowl = wm * 64 + mt * 16 + quad * 4 + r;
                    int coll = wn * 64 + nt * 16 + l16;
                    smem[coll * 136 + rowl] = f2bf(acc[mt][nt][r]);
                }
        __syncthreads();
        int b = mbase >> 10, t0 = mbase & 1023;
        int c = tid >> 1, hf = tid & 1;
        int h = (nloc >> 6) + (c >> 6);
        int a = c & 63;
        u16* dst = vT + ((((size_t)(b * 16 + h)) * 64 + a) << 10) + t0 + hf * 64;
        const u16* srcl = smem + c * 136 + hf * 64;
#pragma unroll
        for (int j = 0; j < 8; j++) *(bf16x8*)(dst + j * 8) = *(const bf16x8*)(srcl + j * 8);
    } else {
        u16* dst = (mat == 0) ? qb : kb;
        float sc = (mat == 0) ? QSCALE : 1.0f;
#pragma unroll
        for (int mt = 0; mt < 4; mt++)
#pragma unroll
            for (int nt = 0; nt < 4; nt++)
#pragma unroll
                for (int r = 0; r < 4; r++) {
                    int gm = mbase + wm * 64 + mt * 16 + quad * 4 + r;
                    int gnl = nloc + wn * 64 + nt * 16 + l16;
                    int b = gm >> 10, t = gm & 1023, h = gnl >> 6, a = gnl & 63;
                    dst[(((size_t)(b * 16 + h) * 1024) + t) * 64 + a] =
                        f2bf(acc[mt][nt][r] * sc);
                }
        if (mat == 1) {
            // ksum[b,h,t] = sum_a K (f32 acc, pre-rounding)
            int h = (nloc + wn * 64) >> 6;
#pragma unroll
            for (int mt = 0; mt < 4; mt++)
#pragma unroll
                for (int r = 0; r < 4; r++) {
                    float s = acc[mt][0][r] + acc[mt][1][r] + acc[mt][2][r] + acc[mt][3][r];
                    s += __shfl_xor(s, 1);
                    s += __shfl_xor(s, 2);
                    s += __shfl_xor(s, 4);
                    s += __shfl_xor(s, 8);
                    if (l16 == 0) {
                        int gm = mbase + wm * 64 + mt * 16 + quad * 4 + r;
                        int b = gm >> 10, t = gm & 1023;
                        ks[(((size_t)(b * 16 + h)) << 10) + t] = s;
                    }
                }
        }
    }
}

// ---------------------------------------------------------------------------
// attn8: attn4's exact per-wave body, widened to 8 waves (q-tile 128, 512
// threads). Rationale (R2-R4 evidence): the cost is the per-iteration
// barrier-drain (mraw HBM latency at sync1, GLDS at sync2), ~1300 of
// ~1875 cyc/block-iter. Halving block-iters per CU (1024 blocks, 4/CU,
// 16 iters each = 64 vs attn4's 128) halves the total drain; K/V L2
// re-reads halve (8 vs 16); staging drops to 2 GLDS/wave. Per-wave
// compute identical to attn4 (16 q-rows, sksm ksum staging, shuffle-lsum
// epilogue); softmax in validated exp2 domain. LDS 35.2 KB -> 4 blocks/CU
// (32 waves, occupancy-capped at max).
// ---------------------------------------------------------------------------
__global__ __launch_bounds__(512) void attn8(const u16* __restrict__ qbuf,
                                             const u16* __restrict__ kbuf,
                                             const u16* __restrict__ vT,
                                             const float* __restrict__ ksum,
                                             const u16* __restrict__ mb,
                                             u16* __restrict__ ctx) {
    __shared__ u16 Ksm[64 * 64];
    __shared__ u16 Vsm[64 * 64];
    __shared__ u16 Psm[8 * 16 * 72];
    __shared__ float sksm[64];
    __shared__ float lsm[128];
    int tid = threadIdx.x;
    int wave = tid >> 6, lane = tid & 63;
    int quad = lane >> 4, l16 = lane & 15;
    int qb = blockIdx.x, h = blockIdx.y, b = blockIdx.z;
    int bh = b * 16 + h;
    const u16* qp = qbuf + (size_t)bh * 65536;
    const u16* kp = kbuf + (size_t)bh * 65536;
    const u16* vp = vT + (size_t)bh * 65536;
    const float* ksp = ksum + (size_t)bh * 1024;
    int q0 = qb * 128 + wave * 16;
    const u16* mbp = mb + ((size_t)b * 1024 + q0 + l16) * 1024;

    bf16x8 qf0 = *(const bf16x8*)(qp + (size_t)(q0 + l16) * 64 + quad * 8);
    bf16x8 qf1 = *(const bf16x8*)(qp + (size_t)(q0 + l16) * 64 + 32 + quad * 8);

    f32x4 oacc[4] = {};
    float lsum = 0.f;
    // staging geometry: wave stages 8 rows (one GLDS each for K and V);
    // lane -> row octet (lane>>3), XOR chunk swizzle (row&7 == r8 invariant)
    int r8 = lane >> 3;
    int sch = (lane & 7) ^ r8;
    u16* lK = Ksm + wave * 512;
    u16* lV = Vsm + wave * 512;
    const u16* gK0 = kp + (size_t)(wave * 8 + r8) * 64 + sch * 8;
    const u16* gV0 = vp + (size_t)(wave * 8 + r8) * 1024 + sch * 8;
    int sx = l16 & 7;
    u16* pw = &Psm[wave * 16 * 72];

    for (int kb = 0; kb < 1024; kb += 64) {
        bf16x4 mraw[4];
#pragma unroll
        for (int nt = 0; nt < 4; nt++)
            mraw[nt] = *(const bf16x4*)(mbp + kb + nt * 16 + quad * 4);
        __syncthreads();  // prev-iter LDS reads done
        GLDS16(gK0 + (size_t)kb * 64, lK);
        GLDS16(gV0 + kb, lV);
        if (tid < 64) sksm[tid] = ksp[kb + tid];
        __syncthreads();  // staging visible

        // S^T = K.Q^T, accumulator pre-biased with exp2-domain offset
        f32x4 sacc[4];
#pragma unroll
        for (int nt = 0; nt < 4; nt++)
            sacc[nt] = f32x4{SOFT_OFF, SOFT_OFF, SOFT_OFF, SOFT_OFF};
#pragma unroll
        for (int nt = 0; nt < 4; nt++) {
            bf16x8 kf0 = *(const bf16x8*)&Ksm[(nt * 16 + l16) * 64 + (quad ^ sx) * 8];
            bf16x8 kf1 = *(const bf16x8*)&Ksm[(nt * 16 + l16) * 64 + ((4 + quad) ^ sx) * 8];
            sacc[nt] = MFMA(kf0, qf0, sacc[nt]);
            sacc[nt] = MFMA(kf1, qf1, sacc[nt]);
        }

        // p = unmasked ? exp2(s + bias*ksum + off) : 0 ; packed bf16 P write
#pragma unroll
        for (int nt = 0; nt < 4; nt++) {
            f32x4 k4 = *(const f32x4*)&sksm[nt * 16 + quad * 4];
            float p[4];
#pragma unroll
            for (int r = 0; r < 4; r++) {
                float f = bf2f((u16)mraw[nt][r]);
                float x = fmaf(f, k4[r], sacc[nt][r]);
                float e = fast_exp2(x);
                p[r] = (f > -1.0e29f) ? e : 0.f;
                lsum += p[r];
            }
            *(u32*)&pw[l16 * 72 + nt * 16 + quad * 4] = pack2bf(p[0], p[1]);
            *(u32*)&pw[l16 * 72 + nt * 16 + quad * 4 + 2] = pack2bf(p[2], p[3]);
        }

        // PV: O += P.V  (wave-private Psm round trip; DS ops in-order)
#pragma unroll
        for (int hs = 0; hs < 2; hs++) {
            bf16x8 pf = *(const bf16x8*)&pw[l16 * 72 + hs * 32 + quad * 8];
#pragma unroll
            for (int at = 0; at < 4; at++) {
                bf16x8 vf = *(const bf16x8*)&Vsm[(at * 16 + l16) * 64 +
                                                 ((hs * 4 + quad) ^ sx) * 8];
                oacc[at] = MFMA(pf, vf, oacc[at]);
            }
        }
    }

    lsum += __shfl_xor(lsum, 16);
    lsum += __shfl_xor(lsum, 32);
    if (lane < 16) lsm[wave * 16 + lane] = lsum;
    __syncthreads();

#pragma unroll
    for (int r = 0; r < 4; r++) {
        float linv = 1.0f / lsm[wave * 16 + quad * 4 + r];
        int q = q0 + quad * 4 + r;
#pragma unroll
        for (int at = 0; at < 4; at++) {
            ctx[(((size_t)b * 1024 + q) * 16 + h) * 64 + at * 16 + l16] =
                f2bf(oacc[at][r] * linv);
        }
    }
}

// ---------------------------------------------------------------------------
// gemmo: output projection, M=8192 N=1024 K=1024, f32 C. Same staging as gemm5.
// ---------------------------------------------------------------------------
__global__ __launch_bounds__(256) void gemmo(const u16* __restrict__ A,
                                             const u16* __restrict__ BT,
                                             float* __restrict__ C) {
    __shared__ u16 Asm[128 * 64];
    __shared__ u16 Bsm[128 * 64];
    int tid = threadIdx.x;
    int wave = tid >> 6, lane = tid & 63;
    int quad = lane >> 4, l16 = lane & 15;
    int wm = wave >> 1, wn = wave & 1;
    int mbase = blockIdx.y * 128, nbase = blockIdx.x * 128;
    f32x4 acc[4][4] = {};
    int srow = wave * 32 + (lane >> 3);
    int schunk = (lane & 7) ^ (lane >> 3);
    const u16* gA = A + (size_t)(mbase + srow) * 1024 + schunk * 8;
    const u16* gB = BT + (size_t)(nbase + srow) * 1024 + schunk * 8;
    u16* lA = Asm + wave * 2048;
    u16* lB = Bsm + wave * 2048;
    int sx = l16 & 7;
    for (int k0 = 0; k0 < 1024; k0 += 64) {
        __syncthreads();
#pragma unroll
        for (int j = 0; j < 4; j++) GLDS16(gA + k0 + j * 8192, lA + j * 512);
#pragma unroll
        for (int j = 0; j < 4; j++) GLDS16(gB + k0 + j * 8192, lB + j * 512);
        __syncthreads();
#pragma unroll
        for (int kk = 0; kk < 2; kk++) {
            bf16x8 af[4], bfr[4];
#pragma unroll
            for (int mt = 0; mt < 4; mt++)
                af[mt] = *(const bf16x8*)&Asm[(wm * 64 + mt * 16 + l16) * 64 +
                                              ((kk * 4 + quad) ^ sx) * 8];
#pragma unroll
            for (int nt = 0; nt < 4; nt++)
                bfr[nt] = *(const bf16x8*)&Bsm[(wn * 64 + nt * 16 + l16) * 64 +
                                               ((kk * 4 + quad) ^ sx) * 8];
#pragma unroll
            for (int mt = 0; mt < 4; mt++)
#pragma unroll
                for (int nt = 0; nt < 4; nt++)
                    acc[mt][nt] = MFMA(af[mt], bfr[nt], acc[mt][nt]);
        }
    }
#pragma unroll
    for (int mt = 0; mt < 4; mt++)
#pragma unroll
        for (int nt = 0; nt < 4; nt++)
#pragma unroll
            for (int r = 0; r < 4; r++) {
                int gm = mbase + wm * 64 + mt * 16 + quad * 4 + r;
                int gn = nbase + wn * 64 + nt * 16 + l16;
                C[(size_t)gm * 1024 + gn] = acc[mt][nt][r];
            }
}

// ---------------------------------------------------------------------------
extern "C" void kernel_launch(void* const* d_in, const int* in_sizes, int n_in,
                              void* d_out, int out_size, void* d_ws, size_t ws_size,
                              hipStream_t stream) {
    const float* states = (const float*)d_in[0];
    const float* key_states = (const float*)d_in[1];
    const float* masks = (const float*)d_in[2];
    const int* abias = (const int*)d_in[3];
    const float* Wq = (const float*)d_in[4];
    const float* Wk = (const float*)d_in[5];
    const float* Wv = (const float*)d_in[6];
    const float* Wout = (const float*)d_in[7];
    const float* be = (const float*)d_in[8];
    const float* bsc = (const float*)d_in[9];

    char* ws = (char*)d_ws;
    size_t off = 0;
    auto alloc = [&](size_t n) { void* p = ws + off; off += (n + 255) & ~(size_t)255; return p; };
    u16* wT = (u16*)alloc(4ull * 1024 * 1024 * 2);          // [Wq|Wk|Wv|Wout]^T bf16 (8 MB)
    u16* sbf = (u16*)alloc((size_t)BB * TT * DD * 2);       // states bf16 (16 MB)
    u16* kbf = (u16*)alloc((size_t)BB * TT * DD * 2);       // key_states bf16 (16 MB)
    u16* qb_ = (u16*)alloc((size_t)BB * HH * TT * AA * 2);  // q [B,H,T,A] (16 MB)
    u16* kb_ = (u16*)alloc((size_t)BB * HH * TT * AA * 2);  // k [B,H,T,A] (16 MB)
    u16* vT_ = (u16*)alloc((size_t)BB * HH * AA * TT * 2);  // vT [B,H,A,T] (16 MB)
    float* ks_ = (float*)alloc((size_t)BB * HH * TT * 4);   // ksum (0.5 MB)
    u16* mb_ = (u16*)alloc((size_t)BB * TT * TT * 2);       // fused mask+bias bf16 (16 MB)

    u16* woT = wT + 3145728;
    int* idx_ = (int*)qb_;   // 32 MB over qb_+kb_ (contiguous, dead until gemm5)
    u16* ctx_ = sbf;         // sbf dead after Q projection

    // 1) fused prep: cvt x2 + mbinit + idx init + tr_w  (all independent)
    prep1<<<dim3(17408), 256, 0, stream>>>(states, key_states, masks, Wq, Wk, Wv,
                                           Wout, sbf, kbf, mb_, idx_, wT);
    // 2) deterministic scatter (last-edge-wins, masked cells excluded)
    scat_max<<<dim3(EE / 256), 256, 0, stream>>>(abias, idx_);
    scat_res<<<dim3(EE / 256), 256, 0, stream>>>(abias, idx_, be, bsc, mb_);
    // 3) fused QKV projection (+ksum epilogue, +V-transpose epilogue)
    gemm5<<<dim3(24, 64), 256, 0, stream>>>(sbf, kbf, wT, qb_, kb_, vT_, ks_);
    // 4) attention (q-tile 128, 8 waves, attn4 body)
    attn8<<<dim3(8, 16, 8), 512, 0, stream>>>(qb_, kb_, vT_, ks_, mb_, ctx_);
    // 5) output projection -> d_out (f32)
    gemmo<<<dim3(8, 64), 256, 0, stream>>>(ctx_, woT, (float*)d_out);
}